// Round 1
// baseline (163.423 us; speedup 1.0000x reference)
//
#include <hip/hip_runtime.h>
#include <math.h>

constexpr int BLOCK = 256;

__global__ __launch_bounds__(BLOCK) void polar3x3_kernel(
    const float* __restrict__ rot,
    const float* __restrict__ mat,
    float* __restrict__ outq,
    float* __restrict__ logdet,
    int N)
{
    __shared__ float lds[BLOCK * 9];
    const int tid = threadIdx.x;
    const long long base = (long long)blockIdx.x * BLOCK;
    int rem = N - (int)base;
    const int nmat = rem < BLOCK ? rem : BLOCK;
    const int nflt = nmat * 9;
    const int nv4 = nflt >> 2;

    // ---- coalesced global -> LDS stage (block base is 16B aligned: 256*36 = 9216) ----
    const float* gsrc = rot + base * 9;
    {
        const float4* g4 = (const float4*)gsrc;
        float4* l4 = (float4*)lds;
        for (int i = tid; i < nv4; i += BLOCK) l4[i] = g4[i];
        for (int i = (nv4 << 2) + tid; i < nflt; i += BLOCK) lds[i] = gsrc[i];
    }
    __syncthreads();

    // uniform 3x3 'mat' in f64 (compiler scalarizes these loads)
    const double m0 = (double)mat[0], m1 = (double)mat[1], m2 = (double)mat[2];
    const double m3 = (double)mat[3], m4 = (double)mat[4], m5 = (double)mat[5];
    const double m6 = (double)mat[6], m7 = (double)mat[7], m8 = (double)mat[8];

    const bool active = tid < nmat;
    // identity default keeps inactive lanes numerically inert through the loop
    float x0=1.f,x1=0.f,x2=0.f,x3=0.f,x4=1.f,x5=0.f,x6=0.f,x7=0.f,x8=1.f;

    if (active) {
        const float* r = &lds[tid * 9];
        const double r0=r[0], r1=r[1], r2=r[2], r3=r[3], r4=r[4],
                     r5=r[5], r6=r[6], r7=r[7], r8=r[8];
        // A = R * M  (f64: the reflection branch of the polar factor is decided
        // by sign(det A); fp32 cancellation can flip it for |det| ~ 1e-7)
        const double a0 = r0*m0 + r1*m3 + r2*m6;
        const double a1 = r0*m1 + r1*m4 + r2*m7;
        const double a2 = r0*m2 + r1*m5 + r2*m8;
        const double a3 = r3*m0 + r4*m3 + r5*m6;
        const double a4 = r3*m1 + r4*m4 + r5*m7;
        const double a5 = r3*m2 + r4*m5 + r5*m8;
        const double a6 = r6*m0 + r7*m3 + r8*m6;
        const double a7 = r6*m1 + r7*m4 + r8*m7;
        const double a8 = r6*m2 + r7*m5 + r8*m8;

        // ---- first (f64) Frobenius-scaled Newton step: X1 = 0.5*(g*A + (1/g)*A^-T)
        // cofactor matrix C: A^-T = C / det
        const double c0 = a4*a8 - a5*a7;
        const double c1 = a5*a6 - a3*a8;
        const double c2 = a3*a7 - a4*a6;
        const double c3 = a2*a7 - a1*a8;
        const double c4 = a0*a8 - a2*a6;
        const double c5 = a1*a6 - a0*a7;
        const double c6 = a1*a5 - a2*a4;
        const double c7 = a2*a3 - a0*a5;
        const double c8 = a0*a4 - a1*a3;
        double det = a0*c0 + a1*c1 + a2*c2;
        double adet = fabs(det);
        adet = fmax(adet, 1e-300);
        det = copysign(adet, det);
        const double nX = sqrt(a0*a0+a1*a1+a2*a2+a3*a3+a4*a4+a5*a5+a6*a6+a7*a7+a8*a8);
        const double nC = sqrt(c0*c0+c1*c1+c2*c2+c3*c3+c4*c4+c5*c5+c6*c6+c7*c7+c8*c8);
        const double g = sqrt(nC / (adet * nX));   // gamma = sqrt(|X^-T|_F / |X|_F)
        const double s = 0.5 * g;
        const double t = 0.5 / (g * det);
        const double y0 = s*a0 + t*c0, y1 = s*a1 + t*c1, y2 = s*a2 + t*c2;
        const double y3 = s*a3 + t*c3, y4 = s*a4 + t*c4, y5 = s*a5 + t*c5;
        const double y6 = s*a6 + t*c6, y7 = s*a7 + t*c7, y8 = s*a8 + t*c8;
        // normalize (scalar scaling is polar-invariant; keeps fp32 in range
        // even when gamma ~ 1e10 for near-singular inputs)
        const double inv = 1.0 / sqrt(y0*y0+y1*y1+y2*y2+y3*y3+y4*y4+y5*y5+y6*y6+y7*y7+y8*y8);
        x0 = (float)(y0*inv); x1 = (float)(y1*inv); x2 = (float)(y2*inv);
        x3 = (float)(y3*inv); x4 = (float)(y4*inv); x5 = (float)(y5*inv);
        x6 = (float)(y6*inv); x7 = (float)(y7*inv); x8 = (float)(y8*inv);
    }
    __syncthreads();   // LDS about to be reused for output

    // ---- fp32 scaled Newton; after step 1, kappa <= ~2.3 => 6 steps reach eps
    #pragma unroll
    for (int it = 0; it < 6; ++it) {
        const float c0 = x4*x8 - x5*x7;
        const float c1 = x5*x6 - x3*x8;
        const float c2 = x3*x7 - x4*x6;
        const float c3 = x2*x7 - x1*x8;
        const float c4 = x0*x8 - x2*x6;
        const float c5 = x1*x6 - x0*x7;
        const float c6 = x1*x5 - x2*x4;
        const float c7 = x2*x3 - x0*x5;
        const float c8 = x0*x4 - x1*x3;
        float det = x0*c0 + x1*c1 + x2*c2;
        float adet = fmaxf(fabsf(det), 1e-30f);
        det = copysignf(adet, det);
        const float nX = sqrtf(x0*x0+x1*x1+x2*x2+x3*x3+x4*x4+x5*x5+x6*x6+x7*x7+x8*x8);
        const float nC = sqrtf(c0*c0+c1*c1+c2*c2+c3*c3+c4*c4+c5*c5+c6*c6+c7*c7+c8*c8);
        const float g = sqrtf(nC / (adet * nX));
        const float s = 0.5f * g;
        const float t = 0.5f / (g * det);
        x0 = s*x0 + t*c0; x1 = s*x1 + t*c1; x2 = s*x2 + t*c2;
        x3 = s*x3 + t*c3; x4 = s*x4 + t*c4; x5 = s*x5 + t*c5;
        x6 = s*x6 + t*c6; x7 = s*x7 + t*c7; x8 = s*x8 + t*c8;
    }

    if (active) {
        float* w = &lds[tid * 9];
        w[0]=x0; w[1]=x1; w[2]=x2; w[3]=x3; w[4]=x4;
        w[5]=x5; w[6]=x6; w[7]=x7; w[8]=x8;
    }
    __syncthreads();

    // ---- coalesced LDS -> global store ----
    float* gdst = outq + base * 9;
    {
        float4* g4 = (float4*)gdst;
        const float4* l4 = (const float4*)lds;
        for (int i = tid; i < nv4; i += BLOCK) g4[i] = l4[i];
        for (int i = (nv4 << 2) + tid; i < nflt; i += BLOCK) gdst[i] = lds[i];
    }

    // logdet = 0 (d_out is poisoned 0xAA every launch; must be written each call)
    if (base + tid < N) logdet[base + tid] = 0.0f;
}

extern "C" void kernel_launch(void* const* d_in, const int* in_sizes, int n_in,
                              void* d_out, int out_size, void* d_ws, size_t ws_size,
                              hipStream_t stream) {
    const float* rot = (const float*)d_in[0];
    const float* mat = (const float*)d_in[1];
    float* out = (float*)d_out;
    const int N = in_sizes[0] / 9;                 // 2,000,000
    float* logdet = out + (long long)N * 9;        // outputs concatenated flat
    const int nblocks = (N + BLOCK - 1) / BLOCK;
    polar3x3_kernel<<<nblocks, BLOCK, 0, stream>>>(rot, mat, out, logdet, N);
}

// Round 2
// 139.341 us; speedup vs baseline: 1.1728x; 1.1728x over previous
//
#include <hip/hip_runtime.h>
#include <math.h>

constexpr int BLOCK = 256;

__global__ __launch_bounds__(BLOCK) void polar3x3_kernel(
    const float* __restrict__ rot,
    const float* __restrict__ mat,
    float* __restrict__ outq,
    float* __restrict__ logdet,
    int N)
{
    const long long idx = (long long)blockIdx.x * BLOCK + threadIdx.x;
    if (idx >= N) return;

    // per-lane 9 contiguous floats; wave's footprint is one contiguous span,
    // every cacheline fully used (gfx950 global loads handle 4B alignment;
    // compiler merges into dwordx4+dwordx4+dword)
    const float* rp = rot + idx * 9;
    const float r0=rp[0], r1=rp[1], r2=rp[2], r3=rp[3], r4=rp[4],
                r5=rp[5], r6=rp[6], r7=rp[7], r8=rp[8];

    // uniform 3x3 'mat' (compiler scalarizes)
    const float m0=mat[0], m1=mat[1], m2=mat[2], m3=mat[3], m4=mat[4],
                m5=mat[5], m6=mat[6], m7=mat[7], m8=mat[8];

    // A = R * M, all f32
    float x0 = fmaf(r0,m0, fmaf(r1,m3, r2*m6));
    float x1 = fmaf(r0,m1, fmaf(r1,m4, r2*m7));
    float x2 = fmaf(r0,m2, fmaf(r1,m5, r2*m8));
    float x3 = fmaf(r3,m0, fmaf(r4,m3, r5*m6));
    float x4 = fmaf(r3,m1, fmaf(r4,m4, r5*m7));
    float x5 = fmaf(r3,m2, fmaf(r4,m5, r5*m8));
    float x6 = fmaf(r6,m0, fmaf(r7,m3, r8*m6));
    float x7 = fmaf(r6,m1, fmaf(r7,m4, r8*m7));
    float x8 = fmaf(r6,m2, fmaf(r7,m5, r8*m8));

    // det(A) = det(R)*det(M) in f64 — the ONLY f64 needed: sign(det) picks the
    // reflection branch of the polar factor; f32 cancellation can flip it for
    // |det| ~ 1e-7. Everything else tolerates f32.
    const double dR = (double)r0*((double)r4*r8 - (double)r5*r7)
                    - (double)r1*((double)r3*r8 - (double)r5*r6)
                    + (double)r2*((double)r3*r7 - (double)r4*r6);
    const double dM = (double)m0*((double)m4*m8 - (double)m5*m7)
                    - (double)m1*((double)m3*m8 - (double)m5*m6)
                    + (double)m2*((double)m3*m7 - (double)m4*m6);
    const float detA = (float)(dR * dM);

    // 6 Frobenius-scaled Newton steps: X <- 0.5*(g*X + (1/g)*X^-T).
    // Scaling factors only need ~1% accuracy (scalar drift is polar-invariant
    // and self-healing; final-step drift is O((g-1)^2)), so use the 1-instr
    // HW approx rcp/rsq/sqrt. Even kappa0=1e9 converges to ~6e-4 in 6 steps.
    #pragma unroll
    for (int it = 0; it < 6; ++it) {
        const float c0 = fmaf(x4,x8, -x5*x7);
        const float c1 = fmaf(x5,x6, -x3*x8);
        const float c2 = fmaf(x3,x7, -x4*x6);
        const float c3 = fmaf(x2,x7, -x1*x8);
        const float c4 = fmaf(x0,x8, -x2*x6);
        const float c5 = fmaf(x1,x6, -x0*x7);
        const float c6 = fmaf(x1,x5, -x2*x4);
        const float c7 = fmaf(x2,x3, -x0*x5);
        const float c8 = fmaf(x0,x4, -x1*x3);
        // det: f64-exact on step 0 (branch decision); after step 0 kappa is
        // modest so the f32 cofactor det has ~eps*kappa relative error — safe.
        const float det = (it == 0) ? detA
                        : fmaf(x0,c0, fmaf(x1,c1, x2*c2));
        const float adet = fmaxf(fabsf(det), 1e-30f);
        const float sdet = copysignf(adet, det);
        float nX2 = x0*x0;
        nX2 = fmaf(x1,x1, nX2); nX2 = fmaf(x2,x2, nX2);
        nX2 = fmaf(x3,x3, nX2); nX2 = fmaf(x4,x4, nX2);
        nX2 = fmaf(x5,x5, nX2); nX2 = fmaf(x6,x6, nX2);
        nX2 = fmaf(x7,x7, nX2); nX2 = fmaf(x8,x8, nX2);
        float nC2 = c0*c0;
        nC2 = fmaf(c1,c1, nC2); nC2 = fmaf(c2,c2, nC2);
        nC2 = fmaf(c3,c3, nC2); nC2 = fmaf(c4,c4, nC2);
        nC2 = fmaf(c5,c5, nC2); nC2 = fmaf(c6,c6, nC2);
        nC2 = fmaf(c7,c7, nC2); nC2 = fmaf(c8,c8, nC2);
        // g = (nC2/nX2)^(1/4) * adet^(-1/2)  == sqrt(|X^-T|_F / |X|_F)
        const float rr = nC2 * __builtin_amdgcn_rcpf(nX2);
        const float g  = __builtin_amdgcn_sqrtf(__builtin_amdgcn_sqrtf(rr))
                       * __builtin_amdgcn_rsqf(adet);
        const float s = 0.5f * g;
        const float t = 0.5f * __builtin_amdgcn_rcpf(g * sdet);
        x0 = fmaf(s,x0, t*c0); x1 = fmaf(s,x1, t*c1); x2 = fmaf(s,x2, t*c2);
        x3 = fmaf(s,x3, t*c3); x4 = fmaf(s,x4, t*c4); x5 = fmaf(s,x5, t*c5);
        x6 = fmaf(s,x6, t*c6); x7 = fmaf(s,x7, t*c7); x8 = fmaf(s,x8, t*c8);
    }

    float* op = outq + idx * 9;
    op[0]=x0; op[1]=x1; op[2]=x2; op[3]=x3; op[4]=x4;
    op[5]=x5; op[6]=x6; op[7]=x7; op[8]=x8;

    // d_out is re-poisoned 0xAA before every launch — must write each call
    logdet[idx] = 0.0f;
}

extern "C" void kernel_launch(void* const* d_in, const int* in_sizes, int n_in,
                              void* d_out, int out_size, void* d_ws, size_t ws_size,
                              hipStream_t stream) {
    const float* rot = (const float*)d_in[0];
    const float* mat = (const float*)d_in[1];
    float* out = (float*)d_out;
    const int N = in_sizes[0] / 9;                 // 2,000,000
    float* logdet = out + (long long)N * 9;        // outputs concatenated flat
    const int nblocks = (N + BLOCK - 1) / BLOCK;
    polar3x3_kernel<<<nblocks, BLOCK, 0, stream>>>(rot, mat, out, logdet, N);
}